// Round 17
// baseline (160.278 us; speedup 1.0000x reference)
//
#include <hip/hip_runtime.h>

typedef _Float16 f16;
typedef _Float16 f16x2 __attribute__((ext_vector_type(2)));
typedef _Float16 f16x4 __attribute__((ext_vector_type(4)));
typedef _Float16 f16x8 __attribute__((ext_vector_type(8)));
typedef float f32x4 __attribute__((ext_vector_type(4)));
typedef unsigned int uint;

#define KM 0.1f   // DT * TAU_MEM_INV
#define KS 0.8f   // 1 - DT * TAU_SYN_INV
#define AS1 __attribute__((address_space(1)))
#define AS3 __attribute__((address_space(3)))
#define EPS_LO 2.44140625e-4f  // 2^-12
#define KCAP0 2560   // L0 per-group K cap (measured ~385/group)
#define KCAP1 2048   // L1 per-group K cap (>= 2000 real cols)
#define KCAP2 1024   // L2 per-group K cap (>= 1000 real cols)

// ---------- E1: enc+LIF0 sim (float4) -> spike bitmask Z[b][f] + per-batch flag words ----------
// flagsB[b][w] (w<375) is OVERWRITTEN by the 8-lane group owning cols w*32..w*32+31 of batch b
// (no zeroing, no atomics). Block 0 also zeroes the flags1/flags2 arrays (used later by epilogues).
__global__ void enc_flags(const float* __restrict__ img, uint* __restrict__ Z,
                          uint* __restrict__ flagsB, uint* __restrict__ flags12, int n12) {
  if (blockIdx.x == 0) {
    for (int i = threadIdx.x; i < n12; i += 256) flags12[i] = 0u;
  }
  int idx = blockIdx.x * 256 + threadIdx.x;
  if (idx >= 128 * 3000) return;
  int b = idx / 3000, f = (idx - b * 3000) << 2;
  float4 t4 = *(const float4*)&img[b * 12000 + f];
  float x[4] = {t4.x, t4.y, t4.z, t4.w};
  float ve[4] = {0.f, 0.f, 0.f, 0.f}, vl[4] = {0.f, 0.f, 0.f, 0.f}, il[4] = {0.f, 0.f, 0.f, 0.f};
  uint m[4] = {0u, 0u, 0u, 0u};
  for (int t = 0; t < 32; ++t) {
#pragma unroll
    for (int e = 0; e < 4; ++e) {
      ve[e] = ve[e] + KM * (x[e] - ve[e]);
      float z0 = (ve[e] > 1.0f) ? 1.f : 0.f;
      ve[e] -= z0 * ve[e];
      float vd = vl[e] + KM * (il[e] - vl[e]);
      float id = KS * il[e];
      float z1 = (vd > 1.0f) ? 1.f : 0.f;
      m[e] |= (vd > 1.0f) ? (1u << t) : 0u;
      vl[e] = (1.f - z1) * vd;
      il[e] = id + z0;
    }
  }
  *(uint4*)&Z[b * 12032 + f] = make_uint4(m[0], m[1], m[2], m[3]);
  uint mask = 0u;
#pragma unroll
  for (int e = 0; e < 4; ++e) mask |= (m[e] ? 1u : 0u) << ((f & 31) + e);
  // 8-lane shuffle-OR: lanes 0..7 share b (3000 % 8 == 0) and one 32-col word
  int lane = threadIdx.x & 63;
#pragma unroll
  for (int s = 1; s < 8; s <<= 1) mask |= (uint)__shfl_xor((int)mask, s);
  if ((lane & 7) == 0) flagsB[b * 375 + (f >> 5)] = mask;  // overwrite, cols<12000 only
}

// ---------- E2: per-group scan: OR `rows` flag-rows, popcount-scan -> colidx_g, meta_g ----------
__global__ void scan_cols(const uint* __restrict__ flagsIn, int* __restrict__ colidxOut,
                          int* __restrict__ metaOut, int nwords, int cstride, int cap,
                          int rows, int rowstride) {
  __shared__ int cnt[512];
  int g = blockIdx.x;
  int* colidx = colidxOut + g * cstride;
  int* meta = metaOut + g * 2;
  int t = threadIdx.x;
  uint w = 0u;
  if (t < nwords) {
    const uint* base = flagsIn + (size_t)g * rows * rowstride + t;
    for (int r = 0; r < rows; ++r) w |= base[r * rowstride];
  }
  cnt[t] = __popc(w);
  __syncthreads();
  for (int off = 1; off < 512; off <<= 1) {
    int v = cnt[t];
    int u = (t >= off) ? cnt[t - off] : 0;
    __syncthreads();
    cnt[t] = v + u;
    __syncthreads();
  }
  int base = cnt[t] - __popc(w);  // exclusive prefix
  uint ww = w;
  int r = 0;
  while (ww) {
    int p = __ffs(ww) - 1;
    colidx[base + r] = t * 32 + p;
    ww &= ww - 1;
    ++r;
  }
  if (t == 511) {
    int K = cnt[511];
    if (K > cap) K = cap;
    meta[0] = K;
    meta[1] = (K + 63) & ~63;
  }
}

// ---------- E3: per-group compacted A_g[512][Kpc_g]; write-coalesced (f16x8 per thread) ----------
__global__ void spike_gather(const uint* __restrict__ Z, f16* __restrict__ A,
                             const int* __restrict__ colidx, const int* __restrict__ meta) {
  int g = blockIdx.y;
  int K = meta[g * 2], Kpc = meta[g * 2 + 1];
  if (Kpc == 0) return;
  const int* cidx = colidx + g * 12032;
  int j8n = Kpc >> 3;
  int total = 512 * j8n;  // 512 rows (= 16 b x 32 t) per group
  for (int i = blockIdx.x * 256 + threadIdx.x; i < total; i += gridDim.x * 256) {
    int row = i / j8n, j8 = (i - row * j8n) << 3;
    int b = g * 16 + (row >> 5), t = row & 31;
    f16x8 s;
#pragma unroll
    for (int e = 0; e < 8; ++e) {
      int j = j8 + e;
      uint m = (j < K) ? Z[b * 12032 + cidx[j]] : 0u;
      s[e] = (f16)(float)((m >> t) & 1u);
    }
    *(f16x8*)&A[g * ((size_t)512 * KCAP0) + (size_t)row * Kpc + j8] = s;
  }
}

// ---------- P: per weight-row block: stage row to LDS once, emit 8 per-group compact hi/lo rows ----------
template <int LROW>
__global__ __launch_bounds__(512) void prep_wk_row(const float* __restrict__ W,
                                                   f16* __restrict__ dst,
                                                   const int* __restrict__ colidx,
                                                   const int* __restrict__ meta,
                                                   int Nr, int Kr, int cstride, size_t bstr) {
  __shared__ float row[LROW];
  int o = blockIdx.x;
  int tid = threadIdx.x;
  bool live = (o < Nr);
  if (live) {
    for (int f4 = tid * 4; f4 < Kr; f4 += 2048)
      *(float4*)&row[f4] = *(const float4*)&W[(size_t)o * Kr + f4];
  }
  __syncthreads();
  int r2 = ((o >> 4) << 5) + (o & 15);  // hi row; +16 = lo row
  for (int g = 0; g < 8; ++g) {
    int K = meta[g * 2], Kpc = meta[g * 2 + 1];
    const int* cidx = colidx + g * cstride;
    f16* dh = dst + g * bstr + (size_t)r2 * Kpc;
    f16* dl = dst + g * bstr + (size_t)(r2 + 16) * Kpc;
    for (int j = tid; j < Kpc; j += 512) {
      float w = 0.f;
      if (live && j < K) {
        int c = cidx[j];
        w = (c < Kr) ? row[c] : 0.f;
      }
      f16 h = (f16)w;
      float hf = (float)h;
      if (__builtin_fabsf(hf) < 6.103515625e-05f) { h = (f16)0.f; hf = 0.f; }
      dh[j] = h;
      dl[j] = (f16)((w - hf) * 4096.0f);
    }
  }
}

// ---------- per-group column gather of dense spike matrix: row = blockIdx.x (4096) ----------
__global__ void gather_cols(const f16* __restrict__ src, f16* __restrict__ dst,
                            const int* __restrict__ colidx, const int* __restrict__ meta,
                            int srcW, int cstride, size_t astr) {
  int row = blockIdx.x;
  int g = row >> 9;
  int K = meta[g * 2], Kpc = meta[g * 2 + 1];
  if (Kpc == 0) return;
  const int* cidx = colidx + g * cstride;
  const f16* s = src + (size_t)row * srcW;
  f16* d = dst + g * astr + (size_t)(row & 511) * Kpc;
  for (int j = threadIdx.x; j < Kpc; j += 256)
    d[j] = (j < K) ? s[cidx[j]] : (f16)0.f;
}

// ---------- weight prep for layers 3..5 (interleaved W2, fixed padded K) ----------
struct PrepArgs {
  const float* W[4];
  f16* dst[4];
  int Nr[4], Kr[4], Kp[4], Npd[4];
  int boff[5];
};

__global__ void prep_w_all(PrepArgs a) {
  int blk = blockIdx.x;
  int k = 0;
#pragma unroll
  for (int j = 0; j < 3; ++j) k += (blk >= a.boff[j + 1]) ? 1 : 0;
  int i = (blk - a.boff[k]) * 256 + threadIdx.x;
  int Kp = a.Kp[k];
  int kp4 = Kp >> 2;
  int total4 = a.Npd[k] * kp4;
  if (i >= total4) return;
  int o = i / kp4, f = (i - o * kp4) << 2;
  float w[4] = {0.f, 0.f, 0.f, 0.f};
  if (o < a.Nr[k] && f < a.Kr[k]) {
    float4 t = *(const float4*)&a.W[k][(size_t)o * a.Kr[k] + f];
    w[0] = t.x; w[1] = t.y; w[2] = t.z; w[3] = t.w;
  }
  f16x4 h4, l4;
#pragma unroll
  for (int e = 0; e < 4; ++e) {
    f16 h = (f16)w[e];
    float hf = (float)h;
    if (__builtin_fabsf(hf) < 6.103515625e-05f) { h = (f16)0.f; hf = 0.f; }
    h4[e] = h;
    l4[e] = (f16)((w[e] - hf) * 4096.0f);
  }
  int r2 = ((o >> 4) << 5) + (o & 15);
  *(f16x4*)&a.dst[k][(size_t)r2 * Kp + f] = h4;
  *(f16x4*)&a.dst[k][(size_t)(r2 + 16) * Kp + f] = l4;
}

// ---------- fused GEMM + LI_k + LIF_{k+1}, templated on wave-rows ----------
template <int WM>
__global__ __launch_bounds__(WM * 128, 4)
void gemm_fused(const f16* __restrict__ A, const f16* __restrict__ B2,
                f16* __restrict__ Spk, float* __restrict__ Out,
                const int* __restrict__ kpcp, int KpFixed, int Np,
                uint* __restrict__ colFlags, int cfw, int grouped,
                size_t astr, size_t bstr) {
  constexpr int BM = WM * 64;
  constexpr int NT = WM * 128;
  constexpr int BI = 1024 / NT;
  __shared__ f16 smem[BM * 64 + 128 * 64];
  f16* sA = smem;
  f16* sB = smem + BM * 64;
  const int tid = threadIdx.x;
  const int lane = tid & 63;
  const int wave = tid >> 6;
  const int wr = wave >> 1;
  const int wc = wave & 1;

  const int nx = gridDim.x;
  const int flat = blockIdx.y * nx + blockIdx.x;
  const int cpx = (nx * gridDim.y) >> 3;
  const int id = (flat & 7) * cpx + (flat >> 3);
  const int m0 = (id / nx) * BM;
  const int n0 = (id % nx) * 128;

  int Kp;
  size_t aoff, boff;
  if (grouped) {
    int g = m0 >> 9;
    Kp = kpcp[g * 2 + 1];
    aoff = g * astr + (size_t)(m0 & 511) * Kp;
    boff = g * bstr + (size_t)n0 * Kp;
  } else {
    Kp = kpcp ? kpcp[1] : KpFixed;
    aoff = (size_t)m0 * Kp;
    boff = (size_t)n0 * Kp;
  }

  f32x4 zero = {0.f, 0.f, 0.f, 0.f};
  f32x4 acc[4][4];
#pragma unroll
  for (int m = 0; m < 4; ++m)
#pragma unroll
    for (int n = 0; n < 4; ++n) acc[m][n] = zero;

  const f16* Abase = A + aoff;
  const f16* Bbase = B2 + boff;
  const int nkt = Kp >> 6;
  for (int kt = 0; kt < nkt; ++kt) {
    __syncthreads();
    const f16* Ab = Abase + (size_t)kt * 64;
    const f16* Bb = Bbase + (size_t)kt * 64;
#pragma unroll
    for (int j = 0; j < 4; ++j) {  // A: BM*8 chunks = 4*NT
      int q = j * NT + tid;
      int r = q >> 3, c = ((q & 7) ^ (r & 7)) * 8;
      __builtin_amdgcn_global_load_lds((const AS1 void*)(Ab + (size_t)r * Kp + c),
                                       (AS3 void*)(&sA[q * 8]), 16, 0, 0);
    }
#pragma unroll
    for (int j = 0; j < BI; ++j) {  // B: 1024 chunks
      int q = j * NT + tid;
      int r = q >> 3, c = ((q & 7) ^ (r & 7)) * 8;
      __builtin_amdgcn_global_load_lds((const AS1 void*)(Bb + (size_t)r * Kp + c),
                                       (AS3 void*)(&sB[q * 8]), 16, 0, 0);
    }
    __syncthreads();
#pragma unroll
    for (int kk = 0; kk < 2; ++kk) {
      const int lr = lane & 15;
      const int hq = lane >> 4;
      f16x8 af[4], bf[4];
#pragma unroll
      for (int m = 0; m < 4; ++m) {
        int R = wr * 64 + m * 16 + lr;
        int ch = (kk * 4 + hq) ^ (R & 7);
        af[m] = *(const f16x8*)&sA[R * 64 + ch * 8];
      }
#pragma unroll
      for (int n = 0; n < 4; ++n) {
        int R = wc * 64 + n * 16 + lr;
        int ch = (kk * 4 + hq) ^ (R & 7);
        bf[n] = *(const f16x8*)&sB[R * 64 + ch * 8];
      }
#pragma unroll
      for (int m = 0; m < 4; ++m)
#pragma unroll
        for (int n = 0; n < 4; ++n)
          acc[m][n] = __builtin_amdgcn_mfma_f32_16x16x32_f16(af[m], bf[n], acc[m][n], 0, 0, 0);
    }
  }

  const int lr = lane & 15, lq = lane >> 4;
  float* scr = (float*)smem + wave * 1152;  // [64][17] f32 per-wave scratch
  const int baseRow = m0 + wr * 64;

  if (Out) {  // last layer: fused LI5 scan + max + log_softmax
    __syncthreads();
#pragma unroll
    for (int m = 0; m < 4; ++m)
#pragma unroll
      for (int i = 0; i < 4; ++i)
        scr[(m * 16 + lq * 4 + i) * 17 + lr] = acc[m][0][i] + EPS_LO * acc[m][1][i];
    __syncthreads();
    float mx = -3.4e38f;
    if (lane < 32) {
      int bl = lane >> 4, c = lane & 15;
      float vL = 0.f, iL = 0.f;
      for (int t = 0; t < 32; ++t) {
        float g = scr[(bl * 32 + t) * 17 + c];
        float ij = iL + g;
        vL = vL + KM * (ij - vL);
        iL = KS * ij;
        mx = fmaxf(mx, vL);
      }
    }
    float v = (lane < 32 && (lane & 15) < 10) ? mx : -3.4e38f;
    float M = v;
#pragma unroll
    for (int s = 1; s < 16; s <<= 1) M = fmaxf(M, __shfl_xor(M, s));
    float e = (lane < 32 && (lane & 15) < 10) ? expf(v - M) : 0.f;
    float sum = e;
#pragma unroll
    for (int s = 1; s < 16; s <<= 1) sum += __shfl_xor(sum, s);
    if (n0 == 0 && wc == 0 && lane < 32 && (lane & 15) < 10) {
      int b = (baseRow >> 5) + (lane >> 4);
      Out[b * 10 + (lane & 15)] = v - M - logf(sum);
    }
    return;
  }

  // ---- fused LI+LIF epilogue: per wave, 64 rows (= 2 batches x 32 t) x 32 cols ----
  __syncthreads();
#pragma unroll
  for (int h = 0; h < 2; ++h) {
#pragma unroll
    for (int m = 0; m < 4; ++m)
#pragma unroll
      for (int i = 0; i < 4; ++i)
        scr[(m * 16 + lq * 4 + i) * 17 + lr] = acc[m][2 * h][i] + EPS_LO * acc[m][2 * h + 1][i];
    __syncthreads();
    if (lane < 32) {
      int bl = lane >> 4, c = lane & 15;
      float vL = 0.f, iL = 0.f, vF = 0.f, iF = 0.f;
      for (int t = 0; t < 32; ++t) {
        float g = scr[(bl * 32 + t) * 17 + c];
        float ij = iL + g;
        vL = vL + KM * (ij - vL);
        iL = KS * ij;
        float vd = vF + KM * (iF - vF);
        float idec = KS * iF;
        float z = (vd > 1.0f) ? 1.f : 0.f;
        vF = (1.f - z) * vd;
        iF = idec + vL;
        scr[(bl * 32 + t) * 17 + c] = z;
      }
    }
    __syncthreads();
    {
      int row = lane;
      f16x8 v0, v1;
#pragma unroll
      for (int cc = 0; cc < 8; ++cc) {
        v0[cc] = (f16)scr[row * 17 + cc];
        v1[cc] = (f16)scr[row * 17 + 8 + cc];
      }
      size_t go = (size_t)(baseRow + row) * Np + (n0 >> 1) + wc * 32 + h * 16;
      *(f16x8*)&Spk[go] = v0;
      *(f16x8*)&Spk[go + 8] = v1;
      if (colFlags) {  // per-group column spike-aliveness for next-layer K compaction
        uint bits = 0u;
#pragma unroll
        for (int cc = 0; cc < 8; ++cc) {
          bits |= (__any((float)v0[cc] != 0.f) ? 1u : 0u) << cc;
          bits |= (__any((float)v1[cc] != 0.f) ? 1u : 0u) << (8 + cc);
        }
        int cstart = (n0 >> 1) + wc * 32 + h * 16;  // multiple of 16
        int g1 = baseRow >> 9;
        if (lane == 0 && bits)
          atomicOr(&colFlags[g1 * cfw + (cstart >> 5)], bits << (cstart & 31));
      }
    }
    __syncthreads();
  }
}

extern "C" void kernel_launch(void* const* d_in, const int* in_sizes, int n_in,
                              void* d_out, int out_size, void* d_ws, size_t ws_size,
                              hipStream_t stream) {
  const float* img = (const float*)d_in[0];

  char* p = (char*)d_ws;
  f16* W0g = (f16*)p; p += 8 * (size_t)4096 * KCAP0 * 2;  // 160 MB
  f16* W1g = (f16*)p; p += 8 * (size_t)3072 * KCAP1 * 2;  // 100.7 MB
  f16* W2g = (f16*)p; p += 8 * (size_t)2048 * KCAP2 * 2;  // 33.6 MB
  f16* W3 = (f16*)p;  p += (size_t)2 * 512 * 1024 * 2;
  f16* W4 = (f16*)p;  p += (size_t)2 * 128 * 512 * 2;
  f16* W5 = (f16*)p;  p += (size_t)2 * 128 * 128 * 2;
  f16* Ag = (f16*)p;  p += 8 * (size_t)512 * KCAP0 * 2;   // 21 MB
  f16* T0 = (f16*)p;  p += (size_t)4096 * 2048 * 2;       // 16.8 MB
  f16* T1 = (f16*)p;  p += (size_t)4096 * 2048 * 2;       // 16.8 MB
  uint* Z = (uint*)p; p += (size_t)128 * 12032 * 4;       // 6.2 MB
  uint* flagsB = (uint*)p; p += (size_t)128 * 375 * 4;    // per-batch L0-in flag words
  uint* flags1 = (uint*)p; p += 8 * 64 * 4;               // L1-in per-group flags
  uint* flags2 = (uint*)p; p += 8 * 48 * 4;               // L2-in per-group flags
  int* colidx = (int*)p;  p += 8 * 12032 * 4;
  int* colidx1 = (int*)p; p += 8 * 2048 * 4;
  int* colidx2 = (int*)p; p += 8 * 1536 * 4;
  int* meta = (int*)p;  p += 16 * 4;
  int* meta1 = (int*)p; p += 16 * 4;
  int* meta2 = (int*)p; p += 16 * 4;

  // --- L0 per-group column compaction chain (no zeroing kernel, no L0 atomics) ---
  enc_flags<<<(128 * 3000 + 255) / 256, 256, 0, stream>>>(img, Z, flagsB, flags1,
                                                          8 * 64 + 8 * 48);
  scan_cols<<<8, 512, 0, stream>>>(flagsB, colidx, meta, 375, 12032, KCAP0, 16, 375);
  spike_gather<<<dim3(128, 8), 256, 0, stream>>>(Z, Ag, colidx, meta);
  prep_wk_row<12032><<<2048, 512, 0, stream>>>((const float*)d_in[1], W0g, colidx, meta,
                                               2000, 12000, 12032, (size_t)4096 * KCAP0);

  // --- layers 3..5 weight prep (fixed padded K) ---
  PrepArgs pa;
  static const int Nr3[3] = {500, 100, 10}, Kr3[3] = {1000, 500, 100};
  static const int Kp3[3] = {1024, 512, 128}, Np3[3] = {512, 128, 128};
  f16* dst3[3] = {W3, W4, W5};
  int nb = 0;
  for (int k = 0; k < 3; ++k) {
    pa.W[k] = (const float*)d_in[k + 4];
    pa.dst[k] = dst3[k];
    pa.Nr[k] = Nr3[k]; pa.Kr[k] = Kr3[k]; pa.Kp[k] = Kp3[k]; pa.Npd[k] = Np3[k];
    pa.boff[k] = nb;
    nb += ((Np3[k] * Kp3[k]) >> 2) / 256;
  }
  pa.boff[3] = nb;
  pa.boff[4] = nb;
  prep_w_all<<<nb, 256, 0, stream>>>(pa);

  // --- L0: grouped GEMM + LI0/LIF1 epilogue + per-group flags1 ---
  gemm_fused<4><<<dim3(32, 16), dim3(512), 0, stream>>>(
      Ag, W0g, T0, nullptr, meta, 0, 2048, flags1, 64, 1,
      (size_t)512 * KCAP0, (size_t)4096 * KCAP0);

  // --- L1 per-group K-compaction ---
  scan_cols<<<8, 512, 0, stream>>>(flags1, colidx1, meta1, 64, 2048, KCAP1, 1, 64);
  gather_cols<<<4096, 256, 0, stream>>>(T0, T1, colidx1, meta1, 2048, 2048,
                                        (size_t)512 * KCAP1);
  prep_wk_row<2048><<<1536, 512, 0, stream>>>((const float*)d_in[2], W1g, colidx1, meta1,
                                              1500, 2000, 2048, (size_t)3072 * KCAP1);

  // --- L1: grouped GEMM + epilogue + per-group flags2 ---
  gemm_fused<4><<<dim3(24, 16), dim3(512), 0, stream>>>(
      T1, W1g, T0, nullptr, meta1, 0, 1536, flags2, 48, 1,
      (size_t)512 * KCAP1, (size_t)3072 * KCAP1);

  // --- L2 per-group K-compaction ---
  scan_cols<<<8, 512, 0, stream>>>(flags2, colidx2, meta2, 48, 1536, KCAP2, 1, 48);
  gather_cols<<<4096, 256, 0, stream>>>(T0, T1, colidx2, meta2, 1536, 1536,
                                        (size_t)512 * KCAP2);
  prep_wk_row<1536><<<1024, 512, 0, stream>>>((const float*)d_in[3], W2g, colidx2, meta2,
                                              1000, 1500, 1536, (size_t)2048 * KCAP2);

  // --- L2: grouped GEMM (WM=2) ---
  gemm_fused<2><<<dim3(16, 32), dim3(256), 0, stream>>>(
      T1, W2g, T0, nullptr, meta2, 0, 1024, nullptr, 0, 1,
      (size_t)512 * KCAP2, (size_t)2048 * KCAP2);

  // --- L3..L5 dense ---
  gemm_fused<2><<<dim3(8, 32), dim3(256), 0, stream>>>(
      T0, W3, T1, nullptr, nullptr, 1024, 512, nullptr, 0, 0, 0, 0);
  gemm_fused<2><<<dim3(2, 32), dim3(256), 0, stream>>>(
      T1, W4, T0, nullptr, nullptr, 512, 128, nullptr, 0, 0, 0, 0);
  gemm_fused<2><<<dim3(2, 32), dim3(256), 0, stream>>>(
      T0, W5, nullptr, (float*)d_out, nullptr, 128, 128, nullptr, 0, 0, 0, 0);
}

// Round 18
// 154.532 us; speedup vs baseline: 1.0372x; 1.0372x over previous
//
#include <hip/hip_runtime.h>

typedef _Float16 f16;
typedef _Float16 f16x2 __attribute__((ext_vector_type(2)));
typedef _Float16 f16x4 __attribute__((ext_vector_type(4)));
typedef _Float16 f16x8 __attribute__((ext_vector_type(8)));
typedef float f32x4 __attribute__((ext_vector_type(4)));
typedef unsigned int uint;

#define KM 0.1f   // DT * TAU_MEM_INV
#define KS 0.8f   // 1 - DT * TAU_SYN_INV
#define AS1 __attribute__((address_space(1)))
#define AS3 __attribute__((address_space(3)))
#define EPS_LO 2.44140625e-4f  // 2^-12
#define KCAP0 2560   // L0 per-group K cap (measured ~385/group)
#define KCAP1 2048   // L1 per-group K cap (>= 2000 real cols)
#define KCAP2 1024   // L2 per-group K cap (>= 1000 real cols)

// ---------- E1: enc+LIF0 sim (float4) -> spike bitmask Z[b][f] + per-batch flag words ----------
__global__ void enc_flags(const float* __restrict__ img, uint* __restrict__ Z,
                          uint* __restrict__ flagsB, uint* __restrict__ flags12, int n12) {
  if (blockIdx.x == 0) {
    for (int i = threadIdx.x; i < n12; i += 256) flags12[i] = 0u;
  }
  int idx = blockIdx.x * 256 + threadIdx.x;
  if (idx >= 128 * 3000) return;
  int b = idx / 3000, f = (idx - b * 3000) << 2;
  float4 t4 = *(const float4*)&img[b * 12000 + f];
  float x[4] = {t4.x, t4.y, t4.z, t4.w};
  float ve[4] = {0.f, 0.f, 0.f, 0.f}, vl[4] = {0.f, 0.f, 0.f, 0.f}, il[4] = {0.f, 0.f, 0.f, 0.f};
  uint m[4] = {0u, 0u, 0u, 0u};
  for (int t = 0; t < 32; ++t) {
#pragma unroll
    for (int e = 0; e < 4; ++e) {
      ve[e] = ve[e] + KM * (x[e] - ve[e]);
      float z0 = (ve[e] > 1.0f) ? 1.f : 0.f;
      ve[e] -= z0 * ve[e];
      float vd = vl[e] + KM * (il[e] - vl[e]);
      float id = KS * il[e];
      float z1 = (vd > 1.0f) ? 1.f : 0.f;
      m[e] |= (vd > 1.0f) ? (1u << t) : 0u;
      vl[e] = (1.f - z1) * vd;
      il[e] = id + z0;
    }
  }
  *(uint4*)&Z[b * 12032 + f] = make_uint4(m[0], m[1], m[2], m[3]);
  uint mask = 0u;
#pragma unroll
  for (int e = 0; e < 4; ++e) mask |= (m[e] ? 1u : 0u) << ((f & 31) + e);
  int lane = threadIdx.x & 63;
#pragma unroll
  for (int s = 1; s < 8; s <<= 1) mask |= (uint)__shfl_xor((int)mask, s);
  if ((lane & 7) == 0) flagsB[b * 375 + (f >> 5)] = mask;  // overwrite, cols<12000 only
}

// ---------- E2: per-group scan: OR `rows` flag-rows, popcount-scan -> colidx_g, meta_g ----------
__global__ void scan_cols(const uint* __restrict__ flagsIn, int* __restrict__ colidxOut,
                          int* __restrict__ metaOut, int nwords, int cstride, int cap,
                          int rows, int rowstride) {
  __shared__ int cnt[512];
  int g = blockIdx.x;
  int* colidx = colidxOut + g * cstride;
  int* meta = metaOut + g * 2;
  int t = threadIdx.x;
  uint w = 0u;
  if (t < nwords) {
    const uint* base = flagsIn + (size_t)g * rows * rowstride + t;
    for (int r = 0; r < rows; ++r) w |= base[r * rowstride];
  }
  cnt[t] = __popc(w);
  __syncthreads();
  for (int off = 1; off < 512; off <<= 1) {
    int v = cnt[t];
    int u = (t >= off) ? cnt[t - off] : 0;
    __syncthreads();
    cnt[t] = v + u;
    __syncthreads();
  }
  int base = cnt[t] - __popc(w);  // exclusive prefix
  uint ww = w;
  int r = 0;
  while (ww) {
    int p = __ffs(ww) - 1;
    colidx[base + r] = t * 32 + p;
    ww &= ww - 1;
    ++r;
  }
  if (t == 511) {
    int K = cnt[511];
    if (K > cap) K = cap;
    meta[0] = K;
    meta[1] = (K + 63) & ~63;
  }
}

// ---------- weight prep args for layers 3..5 ----------
struct PrepArgs {
  const float* W[3];
  f16* dst[3];
  int Nr[3], Kr[3], Kp[3], Npd[3];
  int boff[4];  // block offsets in 512-thread units
};

// ---------- merged L0 prep: [0,2048) prep W0 rows | [2048,3072) spike_gather | [3072,+) prep L3-5 ----------
__global__ __launch_bounds__(512) void prep0_all(const float* __restrict__ W,
                                                 f16* __restrict__ W0g,
                                                 const uint* __restrict__ Z,
                                                 f16* __restrict__ Ag,
                                                 const int* __restrict__ colidx,
                                                 const int* __restrict__ meta,
                                                 PrepArgs pa) {
  __shared__ float row[12032];  // 48128 B (used by branch 1 only)
  int blk = blockIdx.x;
  int tid = threadIdx.x;

  if (blk < 2048) {  // ---- prep_w0_row: one weight row, 8 per-group compact hi/lo rows ----
    int o = blk;
    bool live = (o < 2000);
    if (live) {
      for (int f4 = tid * 4; f4 < 12000; f4 += 2048)
        *(float4*)&row[f4] = *(const float4*)&W[(size_t)o * 12000 + f4];
    }
    __syncthreads();
    int r2 = ((o >> 4) << 5) + (o & 15);
    for (int g = 0; g < 8; ++g) {
      int K = meta[g * 2], Kpc = meta[g * 2 + 1];
      const int* cidx = colidx + g * 12032;
      f16* dh = W0g + g * ((size_t)4096 * KCAP0) + (size_t)r2 * Kpc;
      f16* dl = W0g + g * ((size_t)4096 * KCAP0) + (size_t)(r2 + 16) * Kpc;
      for (int j = tid; j < Kpc; j += 512) {
        float w = (live && j < K) ? row[cidx[j]] : 0.f;
        f16 h = (f16)w;
        float hf = (float)h;
        if (__builtin_fabsf(hf) < 6.103515625e-05f) { h = (f16)0.f; hf = 0.f; }
        dh[j] = h;
        dl[j] = (f16)((w - hf) * 4096.0f);
      }
    }
    return;
  }

  if (blk < 3072) {  // ---- spike_gather: per-group compacted A, write-coalesced ----
    int lb = blk - 2048;
    int g = lb >> 7, xb = lb & 127;
    int K = meta[g * 2], Kpc = meta[g * 2 + 1];
    if (Kpc == 0) return;
    const int* cidx = colidx + g * 12032;
    int j8n = Kpc >> 3;
    int total = 512 * j8n;
    for (int i = xb * 512 + tid; i < total; i += 128 * 512) {
      int r = i / j8n, j8 = (i - r * j8n) << 3;
      int b = g * 16 + (r >> 5), t = r & 31;
      f16x8 s;
#pragma unroll
      for (int e = 0; e < 8; ++e) {
        int j = j8 + e;
        uint m = (j < K) ? Z[b * 12032 + cidx[j]] : 0u;
        s[e] = (f16)(float)((m >> t) & 1u);
      }
      *(f16x8*)&Ag[g * ((size_t)512 * KCAP0) + (size_t)r * Kpc + j8] = s;
    }
    return;
  }

  {  // ---- prep_w_all for L3..L5 (interleaved W2, fixed padded K), 512-thr indexing ----
    int lb = blk - 3072;
    int k = 0;
#pragma unroll
    for (int j = 0; j < 2; ++j) k += (lb >= pa.boff[j + 1]) ? 1 : 0;
    int i = (lb - pa.boff[k]) * 512 + tid;
    int Kp = pa.Kp[k];
    int kp4 = Kp >> 2;
    int total4 = pa.Npd[k] * kp4;
    if (i >= total4) return;
    int o = i / kp4, f = (i - o * kp4) << 2;
    float w[4] = {0.f, 0.f, 0.f, 0.f};
    if (o < pa.Nr[k] && f < pa.Kr[k]) {
      float4 t = *(const float4*)&pa.W[k][(size_t)o * pa.Kr[k] + f];
      w[0] = t.x; w[1] = t.y; w[2] = t.z; w[3] = t.w;
    }
    f16x4 h4, l4;
#pragma unroll
    for (int e = 0; e < 4; ++e) {
      f16 h = (f16)w[e];
      float hf = (float)h;
      if (__builtin_fabsf(hf) < 6.103515625e-05f) { h = (f16)0.f; hf = 0.f; }
      h4[e] = h;
      l4[e] = (f16)((w[e] - hf) * 4096.0f);
    }
    int r2 = ((o >> 4) << 5) + (o & 15);
    *(f16x4*)&pa.dst[k][(size_t)r2 * Kp + f] = h4;
    *(f16x4*)&pa.dst[k][(size_t)(r2 + 16) * Kp + f] = l4;
  }
}

// ---------- merged Lk prep (k=1,2): [0,4096) gather spike cols | [4096,+) prep Wk rows ----------
__global__ __launch_bounds__(512) void prepk_all(const f16* __restrict__ src,
                                                 f16* __restrict__ dst,
                                                 const float* __restrict__ W,
                                                 f16* __restrict__ Wg,
                                                 const int* __restrict__ colidx,
                                                 const int* __restrict__ meta,
                                                 int srcW, int cstride, size_t astr,
                                                 int Nr, int Kr, size_t bstr) {
  __shared__ float row[2048];  // 8 KB (used by prep branch only)
  int blk = blockIdx.x;
  int tid = threadIdx.x;

  if (blk < 4096) {  // ---- gather_cols: one spike row ----
    int r = blk;
    int g = r >> 9;
    int K = meta[g * 2], Kpc = meta[g * 2 + 1];
    if (Kpc == 0) return;
    const int* cidx = colidx + g * cstride;
    const f16* s = src + (size_t)r * srcW;
    f16* d = dst + g * astr + (size_t)(r & 511) * Kpc;
    for (int j = tid; j < Kpc; j += 512)
      d[j] = (j < K) ? s[cidx[j]] : (f16)0.f;
    return;
  }

  {  // ---- prep_wk_row: one weight row, 8 per-group compact hi/lo rows ----
    int o = blk - 4096;
    bool live = (o < Nr);
    if (live) {
      for (int f4 = tid * 4; f4 < Kr; f4 += 2048)
        *(float4*)&row[f4] = *(const float4*)&W[(size_t)o * Kr + f4];
    }
    __syncthreads();
    int r2 = ((o >> 4) << 5) + (o & 15);
    for (int g = 0; g < 8; ++g) {
      int K = meta[g * 2], Kpc = meta[g * 2 + 1];
      const int* cidx = colidx + g * cstride;
      f16* dh = Wg + g * bstr + (size_t)r2 * Kpc;
      f16* dl = Wg + g * bstr + (size_t)(r2 + 16) * Kpc;
      for (int j = tid; j < Kpc; j += 512) {
        float w = 0.f;
        if (live && j < K) {
          int c = cidx[j];
          w = (c < Kr) ? row[c] : 0.f;
        }
        f16 h = (f16)w;
        float hf = (float)h;
        if (__builtin_fabsf(hf) < 6.103515625e-05f) { h = (f16)0.f; hf = 0.f; }
        dh[j] = h;
        dl[j] = (f16)((w - hf) * 4096.0f);
      }
    }
  }
}

// ---------- fused GEMM + LI_k + LIF_{k+1}, templated on wave-rows ----------
template <int WM>
__global__ __launch_bounds__(WM * 128, 4)
void gemm_fused(const f16* __restrict__ A, const f16* __restrict__ B2,
                f16* __restrict__ Spk, float* __restrict__ Out,
                const int* __restrict__ kpcp, int KpFixed, int Np,
                uint* __restrict__ colFlags, int cfw, int grouped,
                size_t astr, size_t bstr) {
  constexpr int BM = WM * 64;
  constexpr int NT = WM * 128;
  constexpr int BI = 1024 / NT;
  __shared__ f16 smem[BM * 64 + 128 * 64];
  f16* sA = smem;
  f16* sB = smem + BM * 64;
  const int tid = threadIdx.x;
  const int lane = tid & 63;
  const int wave = tid >> 6;
  const int wr = wave >> 1;
  const int wc = wave & 1;

  const int nx = gridDim.x;
  const int flat = blockIdx.y * nx + blockIdx.x;
  const int cpx = (nx * gridDim.y) >> 3;
  const int id = (flat & 7) * cpx + (flat >> 3);
  const int m0 = (id / nx) * BM;
  const int n0 = (id % nx) * 128;

  int Kp;
  size_t aoff, boff;
  if (grouped) {
    int g = m0 >> 9;
    Kp = kpcp[g * 2 + 1];
    aoff = g * astr + (size_t)(m0 & 511) * Kp;
    boff = g * bstr + (size_t)n0 * Kp;
  } else {
    Kp = kpcp ? kpcp[1] : KpFixed;
    aoff = (size_t)m0 * Kp;
    boff = (size_t)n0 * Kp;
  }

  f32x4 zero = {0.f, 0.f, 0.f, 0.f};
  f32x4 acc[4][4];
#pragma unroll
  for (int m = 0; m < 4; ++m)
#pragma unroll
    for (int n = 0; n < 4; ++n) acc[m][n] = zero;

  const f16* Abase = A + aoff;
  const f16* Bbase = B2 + boff;
  const int nkt = Kp >> 6;
  for (int kt = 0; kt < nkt; ++kt) {
    __syncthreads();
    const f16* Ab = Abase + (size_t)kt * 64;
    const f16* Bb = Bbase + (size_t)kt * 64;
#pragma unroll
    for (int j = 0; j < 4; ++j) {  // A: BM*8 chunks = 4*NT
      int q = j * NT + tid;
      int r = q >> 3, c = ((q & 7) ^ (r & 7)) * 8;
      __builtin_amdgcn_global_load_lds((const AS1 void*)(Ab + (size_t)r * Kp + c),
                                       (AS3 void*)(&sA[q * 8]), 16, 0, 0);
    }
#pragma unroll
    for (int j = 0; j < BI; ++j) {  // B: 1024 chunks
      int q = j * NT + tid;
      int r = q >> 3, c = ((q & 7) ^ (r & 7)) * 8;
      __builtin_amdgcn_global_load_lds((const AS1 void*)(Bb + (size_t)r * Kp + c),
                                       (AS3 void*)(&sB[q * 8]), 16, 0, 0);
    }
    __syncthreads();
#pragma unroll
    for (int kk = 0; kk < 2; ++kk) {
      const int lr = lane & 15;
      const int hq = lane >> 4;
      f16x8 af[4], bf[4];
#pragma unroll
      for (int m = 0; m < 4; ++m) {
        int R = wr * 64 + m * 16 + lr;
        int ch = (kk * 4 + hq) ^ (R & 7);
        af[m] = *(const f16x8*)&sA[R * 64 + ch * 8];
      }
#pragma unroll
      for (int n = 0; n < 4; ++n) {
        int R = wc * 64 + n * 16 + lr;
        int ch = (kk * 4 + hq) ^ (R & 7);
        bf[n] = *(const f16x8*)&sB[R * 64 + ch * 8];
      }
#pragma unroll
      for (int m = 0; m < 4; ++m)
#pragma unroll
        for (int n = 0; n < 4; ++n)
          acc[m][n] = __builtin_amdgcn_mfma_f32_16x16x32_f16(af[m], bf[n], acc[m][n], 0, 0, 0);
    }
  }

  const int lr = lane & 15, lq = lane >> 4;
  float* scr = (float*)smem + wave * 1152;  // [64][17] f32 per-wave scratch
  const int baseRow = m0 + wr * 64;

  if (Out) {  // last layer: fused LI5 scan + max + log_softmax
    __syncthreads();
#pragma unroll
    for (int m = 0; m < 4; ++m)
#pragma unroll
      for (int i = 0; i < 4; ++i)
        scr[(m * 16 + lq * 4 + i) * 17 + lr] = acc[m][0][i] + EPS_LO * acc[m][1][i];
    __syncthreads();
    float mx = -3.4e38f;
    if (lane < 32) {
      int bl = lane >> 4, c = lane & 15;
      float vL = 0.f, iL = 0.f;
      for (int t = 0; t < 32; ++t) {
        float g = scr[(bl * 32 + t) * 17 + c];
        float ij = iL + g;
        vL = vL + KM * (ij - vL);
        iL = KS * ij;
        mx = fmaxf(mx, vL);
      }
    }
    float v = (lane < 32 && (lane & 15) < 10) ? mx : -3.4e38f;
    float M = v;
#pragma unroll
    for (int s = 1; s < 16; s <<= 1) M = fmaxf(M, __shfl_xor(M, s));
    float e = (lane < 32 && (lane & 15) < 10) ? expf(v - M) : 0.f;
    float sum = e;
#pragma unroll
    for (int s = 1; s < 16; s <<= 1) sum += __shfl_xor(sum, s);
    if (n0 == 0 && wc == 0 && lane < 32 && (lane & 15) < 10) {
      int b = (baseRow >> 5) + (lane >> 4);
      Out[b * 10 + (lane & 15)] = v - M - logf(sum);
    }
    return;
  }

  // ---- fused LI+LIF epilogue: per wave, 64 rows (= 2 batches x 32 t) x 32 cols ----
  __syncthreads();
#pragma unroll
  for (int h = 0; h < 2; ++h) {
#pragma unroll
    for (int m = 0; m < 4; ++m)
#pragma unroll
      for (int i = 0; i < 4; ++i)
        scr[(m * 16 + lq * 4 + i) * 17 + lr] = acc[m][2 * h][i] + EPS_LO * acc[m][2 * h + 1][i];
    __syncthreads();
    if (lane < 32) {
      int bl = lane >> 4, c = lane & 15;
      float vL = 0.f, iL = 0.f, vF = 0.f, iF = 0.f;
      for (int t = 0; t < 32; ++t) {
        float g = scr[(bl * 32 + t) * 17 + c];
        float ij = iL + g;
        vL = vL + KM * (ij - vL);
        iL = KS * ij;
        float vd = vF + KM * (iF - vF);
        float idec = KS * iF;
        float z = (vd > 1.0f) ? 1.f : 0.f;
        vF = (1.f - z) * vd;
        iF = idec + vL;
        scr[(bl * 32 + t) * 17 + c] = z;
      }
    }
    __syncthreads();
    {
      int row = lane;
      f16x8 v0, v1;
#pragma unroll
      for (int cc = 0; cc < 8; ++cc) {
        v0[cc] = (f16)scr[row * 17 + cc];
        v1[cc] = (f16)scr[row * 17 + 8 + cc];
      }
      size_t go = (size_t)(baseRow + row) * Np + (n0 >> 1) + wc * 32 + h * 16;
      *(f16x8*)&Spk[go] = v0;
      *(f16x8*)&Spk[go + 8] = v1;
      if (colFlags) {  // per-group column spike-aliveness for next-layer K compaction
        uint bits = 0u;
#pragma unroll
        for (int cc = 0; cc < 8; ++cc) {
          bits |= (__any((float)v0[cc] != 0.f) ? 1u : 0u) << cc;
          bits |= (__any((float)v1[cc] != 0.f) ? 1u : 0u) << (8 + cc);
        }
        int cstart = (n0 >> 1) + wc * 32 + h * 16;  // multiple of 16
        int g1 = baseRow >> 9;
        if (lane == 0 && bits)
          atomicOr(&colFlags[g1 * cfw + (cstart >> 5)], bits << (cstart & 31));
      }
    }
    __syncthreads();
  }
}

extern "C" void kernel_launch(void* const* d_in, const int* in_sizes, int n_in,
                              void* d_out, int out_size, void* d_ws, size_t ws_size,
                              hipStream_t stream) {
  const float* img = (const float*)d_in[0];

  char* p = (char*)d_ws;
  f16* W0g = (f16*)p; p += 8 * (size_t)4096 * KCAP0 * 2;  // 160 MB
  f16* W1g = (f16*)p; p += 8 * (size_t)3072 * KCAP1 * 2;  // 100.7 MB
  f16* W2g = (f16*)p; p += 8 * (size_t)2048 * KCAP2 * 2;  // 33.6 MB
  f16* W3 = (f16*)p;  p += (size_t)2 * 512 * 1024 * 2;
  f16* W4 = (f16*)p;  p += (size_t)2 * 128 * 512 * 2;
  f16* W5 = (f16*)p;  p += (size_t)2 * 128 * 128 * 2;
  f16* Ag = (f16*)p;  p += 8 * (size_t)512 * KCAP0 * 2;   // 21 MB
  f16* T0 = (f16*)p;  p += (size_t)4096 * 2048 * 2;       // 16.8 MB
  f16* T1 = (f16*)p;  p += (size_t)4096 * 2048 * 2;       // 16.8 MB
  uint* Z = (uint*)p; p += (size_t)128 * 12032 * 4;       // 6.2 MB
  uint* flagsB = (uint*)p; p += (size_t)128 * 375 * 4;    // per-batch L0-in flag words
  uint* flags1 = (uint*)p; p += 8 * 64 * 4;               // L1-in per-group flags
  uint* flags2 = (uint*)p; p += 8 * 48 * 4;               // L2-in per-group flags
  int* colidx = (int*)p;  p += 8 * 12032 * 4;
  int* colidx1 = (int*)p; p += 8 * 2048 * 4;
  int* colidx2 = (int*)p; p += 8 * 1536 * 4;
  int* meta = (int*)p;  p += 16 * 4;
  int* meta1 = (int*)p; p += 16 * 4;
  int* meta2 = (int*)p; p += 16 * 4;

  // --- enc + L0 flag scan ---
  enc_flags<<<(128 * 3000 + 255) / 256, 256, 0, stream>>>(img, Z, flagsB, flags1,
                                                          8 * 64 + 8 * 48);
  scan_cols<<<8, 512, 0, stream>>>(flagsB, colidx, meta, 375, 12032, KCAP0, 16, 375);

  // --- merged L0 prep: W0 compaction + spike gather + L3-5 weight prep ---
  PrepArgs pa;
  static const int Nr3[3] = {500, 100, 10}, Kr3[3] = {1000, 500, 100};
  static const int Kp3[3] = {1024, 512, 128}, Np3[3] = {512, 128, 128};
  f16* dst3[3] = {W3, W4, W5};
  int nb = 0;
  for (int k = 0; k < 3; ++k) {
    pa.W[k] = (const float*)d_in[k + 4];
    pa.dst[k] = dst3[k];
    pa.Nr[k] = Nr3[k]; pa.Kr[k] = Kr3[k]; pa.Kp[k] = Kp3[k]; pa.Npd[k] = Np3[k];
    pa.boff[k] = nb;
    nb += ((Np3[k] * Kp3[k]) >> 2) / 512;  // 256, 32, 8 blocks
  }
  pa.boff[3] = nb;
  prep0_all<<<3072 + nb, 512, 0, stream>>>((const float*)d_in[1], W0g, Z, Ag,
                                           colidx, meta, pa);

  // --- L0: grouped GEMM + LI0/LIF1 epilogue + per-group flags1 ---
  gemm_fused<4><<<dim3(32, 16), dim3(512), 0, stream>>>(
      Ag, W0g, T0, nullptr, meta, 0, 2048, flags1, 64, 1,
      (size_t)512 * KCAP0, (size_t)4096 * KCAP0);

  // --- L1 per-group K-compaction (merged gather + prep) ---
  scan_cols<<<8, 512, 0, stream>>>(flags1, colidx1, meta1, 64, 2048, KCAP1, 1, 64);
  prepk_all<<<4096 + 1536, 512, 0, stream>>>(T0, T1, (const float*)d_in[2], W1g,
                                             colidx1, meta1, 2048, 2048,
                                             (size_t)512 * KCAP1, 1500, 2000,
                                             (size_t)3072 * KCAP1);

  // --- L1: grouped GEMM + epilogue + per-group flags2 ---
  gemm_fused<4><<<dim3(24, 16), dim3(512), 0, stream>>>(
      T1, W1g, T0, nullptr, meta1, 0, 1536, flags2, 48, 1,
      (size_t)512 * KCAP1, (size_t)3072 * KCAP1);

  // --- L2 per-group K-compaction (merged gather + prep) ---
  scan_cols<<<8, 512, 0, stream>>>(flags2, colidx2, meta2, 48, 1536, KCAP2, 1, 48);
  prepk_all<<<4096 + 1024, 512, 0, stream>>>(T0, T1, (const float*)d_in[3], W2g,
                                             colidx2, meta2, 1536, 1536,
                                             (size_t)512 * KCAP2, 1000, 1500,
                                             (size_t)2048 * KCAP2);

  // --- L2: grouped GEMM (WM=2) ---
  gemm_fused<2><<<dim3(16, 32), dim3(256), 0, stream>>>(
      T1, W2g, T0, nullptr, meta2, 0, 1024, nullptr, 0, 1,
      (size_t)512 * KCAP2, (size_t)2048 * KCAP2);

  // --- L3..L5 dense ---
  gemm_fused<2><<<dim3(8, 32), dim3(256), 0, stream>>>(
      T0, W3, T1, nullptr, nullptr, 1024, 512, nullptr, 0, 0, 0, 0);
  gemm_fused<2><<<dim3(2, 32), dim3(256), 0, stream>>>(
      T1, W4, T0, nullptr, nullptr, 512, 128, nullptr, 0, 0, 0, 0);
  gemm_fused<2><<<dim3(2, 32), dim3(256), 0, stream>>>(
      T0, W5, nullptr, (float*)d_out, nullptr, 128, 128, nullptr, 0, 0, 0, 0);
}

// Round 19
// 143.579 us; speedup vs baseline: 1.1163x; 1.0763x over previous
//
#include <hip/hip_runtime.h>

typedef _Float16 f16;
typedef _Float16 f16x2 __attribute__((ext_vector_type(2)));
typedef _Float16 f16x4 __attribute__((ext_vector_type(4)));
typedef _Float16 f16x8 __attribute__((ext_vector_type(8)));
typedef float f32x4 __attribute__((ext_vector_type(4)));
typedef unsigned int uint;

#define KM 0.1f   // DT * TAU_MEM_INV
#define KS 0.8f   // 1 - DT * TAU_SYN_INV
#define AS1 __attribute__((address_space(1)))
#define AS3 __attribute__((address_space(3)))
#define EPS_LO 2.44140625e-4f  // 2^-12
#define KCAP0 2560   // L0 per-group K cap (measured ~385/group)
#define KCAP1 2048   // L1 per-group K cap (>= 2000 real cols)
#define KCAP2 1024   // L2 per-group K cap (>= 1000 real cols)
#define KCAP3 1024   // L3 per-group K cap (>= 1000 real cols)

// ---------- E1: enc+LIF0 sim (float4) -> spike bitmask Z[b][f] + per-batch flag words ----------
__global__ void enc_flags(const float* __restrict__ img, uint* __restrict__ Z,
                          uint* __restrict__ flagsB, uint* __restrict__ flags123, int n123) {
  if (blockIdx.x == 0) {
    for (int i = threadIdx.x; i < n123; i += 256) flags123[i] = 0u;
  }
  int idx = blockIdx.x * 256 + threadIdx.x;
  if (idx >= 128 * 3000) return;
  int b = idx / 3000, f = (idx - b * 3000) << 2;
  float4 t4 = *(const float4*)&img[b * 12000 + f];
  float x[4] = {t4.x, t4.y, t4.z, t4.w};
  float ve[4] = {0.f, 0.f, 0.f, 0.f}, vl[4] = {0.f, 0.f, 0.f, 0.f}, il[4] = {0.f, 0.f, 0.f, 0.f};
  uint m[4] = {0u, 0u, 0u, 0u};
  for (int t = 0; t < 32; ++t) {
#pragma unroll
    for (int e = 0; e < 4; ++e) {
      ve[e] = ve[e] + KM * (x[e] - ve[e]);
      float z0 = (ve[e] > 1.0f) ? 1.f : 0.f;
      ve[e] -= z0 * ve[e];
      float vd = vl[e] + KM * (il[e] - vl[e]);
      float id = KS * il[e];
      float z1 = (vd > 1.0f) ? 1.f : 0.f;
      m[e] |= (vd > 1.0f) ? (1u << t) : 0u;
      vl[e] = (1.f - z1) * vd;
      il[e] = id + z0;
    }
  }
  *(uint4*)&Z[b * 12032 + f] = make_uint4(m[0], m[1], m[2], m[3]);
  uint mask = 0u;
#pragma unroll
  for (int e = 0; e < 4; ++e) mask |= (m[e] ? 1u : 0u) << ((f & 31) + e);
  int lane = threadIdx.x & 63;
#pragma unroll
  for (int s = 1; s < 8; s <<= 1) mask |= (uint)__shfl_xor((int)mask, s);
  if ((lane & 7) == 0) flagsB[b * 375 + (f >> 5)] = mask;  // overwrite, cols<12000 only
}

// ---------- E2: per-group scan: OR `rows` flag-rows, popcount-scan -> colidx_g, meta_g ----------
__global__ void scan_cols(const uint* __restrict__ flagsIn, int* __restrict__ colidxOut,
                          int* __restrict__ metaOut, int nwords, int cstride, int cap,
                          int rows, int rowstride) {
  __shared__ int cnt[512];
  int g = blockIdx.x;
  int* colidx = colidxOut + g * cstride;
  int* meta = metaOut + g * 2;
  int t = threadIdx.x;
  uint w = 0u;
  if (t < nwords) {
    const uint* base = flagsIn + (size_t)g * rows * rowstride + t;
    for (int r = 0; r < rows; ++r) w |= base[r * rowstride];
  }
  cnt[t] = __popc(w);
  __syncthreads();
  for (int off = 1; off < 512; off <<= 1) {
    int v = cnt[t];
    int u = (t >= off) ? cnt[t - off] : 0;
    __syncthreads();
    cnt[t] = v + u;
    __syncthreads();
  }
  int base = cnt[t] - __popc(w);  // exclusive prefix
  uint ww = w;
  int r = 0;
  while (ww) {
    int p = __ffs(ww) - 1;
    colidx[base + r] = t * 32 + p;
    ww &= ww - 1;
    ++r;
  }
  if (t == 511) {
    int K = cnt[511];
    if (K > cap) K = cap;
    meta[0] = K;
    meta[1] = (K + 63) & ~63;
  }
}

// ---------- weight prep args for layers 4..5 ----------
struct PrepArgs {
  const float* W[2];
  f16* dst[2];
  int Nr[2], Kr[2], Kp[2], Npd[2];
  int boff[3];  // block offsets in 512-thread units
};

// ---------- merged L0 prep: [0,2048) prep W0 rows | [2048,3072) spike_gather | [3072,+) prep L4-5 ----------
__global__ __launch_bounds__(512) void prep0_all(const float* __restrict__ W,
                                                 f16* __restrict__ W0g,
                                                 const uint* __restrict__ Z,
                                                 f16* __restrict__ Ag,
                                                 const int* __restrict__ colidx,
                                                 const int* __restrict__ meta,
                                                 PrepArgs pa) {
  __shared__ float row[12032];  // 48128 B (used by branch 1 only)
  int blk = blockIdx.x;
  int tid = threadIdx.x;

  if (blk < 2048) {  // ---- prep_w0_row: one weight row, 8 per-group compact hi/lo rows ----
    int o = blk;
    bool live = (o < 2000);
    if (live) {
      for (int f4 = tid * 4; f4 < 12000; f4 += 2048)
        *(float4*)&row[f4] = *(const float4*)&W[(size_t)o * 12000 + f4];
    }
    __syncthreads();
    int r2 = ((o >> 4) << 5) + (o & 15);
    for (int g = 0; g < 8; ++g) {
      int K = meta[g * 2], Kpc = meta[g * 2 + 1];
      const int* cidx = colidx + g * 12032;
      f16* dh = W0g + g * ((size_t)4096 * KCAP0) + (size_t)r2 * Kpc;
      f16* dl = W0g + g * ((size_t)4096 * KCAP0) + (size_t)(r2 + 16) * Kpc;
      for (int j = tid; j < Kpc; j += 512) {
        float w = (live && j < K) ? row[cidx[j]] : 0.f;
        f16 h = (f16)w;
        float hf = (float)h;
        if (__builtin_fabsf(hf) < 6.103515625e-05f) { h = (f16)0.f; hf = 0.f; }
        dh[j] = h;
        dl[j] = (f16)((w - hf) * 4096.0f);
      }
    }
    return;
  }

  if (blk < 3072) {  // ---- spike_gather: per-group compacted A, write-coalesced ----
    int lb = blk - 2048;
    int g = lb >> 7, xb = lb & 127;
    int K = meta[g * 2], Kpc = meta[g * 2 + 1];
    if (Kpc == 0) return;
    const int* cidx = colidx + g * 12032;
    int j8n = Kpc >> 3;
    int total = 512 * j8n;
    for (int i = xb * 512 + tid; i < total; i += 128 * 512) {
      int r = i / j8n, j8 = (i - r * j8n) << 3;
      int b = g * 16 + (r >> 5), t = r & 31;
      f16x8 s;
#pragma unroll
      for (int e = 0; e < 8; ++e) {
        int j = j8 + e;
        uint m = (j < K) ? Z[b * 12032 + cidx[j]] : 0u;
        s[e] = (f16)(float)((m >> t) & 1u);
      }
      *(f16x8*)&Ag[g * ((size_t)512 * KCAP0) + (size_t)r * Kpc + j8] = s;
    }
    return;
  }

  {  // ---- prep for L4..L5 (interleaved W2, fixed padded K), 512-thr indexing ----
    int lb = blk - 3072;
    int k = (lb >= pa.boff[1]) ? 1 : 0;
    int i = (lb - pa.boff[k]) * 512 + tid;
    int Kp = pa.Kp[k];
    int kp4 = Kp >> 2;
    int total4 = pa.Npd[k] * kp4;
    if (i >= total4) return;
    int o = i / kp4, f = (i - o * kp4) << 2;
    float w[4] = {0.f, 0.f, 0.f, 0.f};
    if (o < pa.Nr[k] && f < pa.Kr[k]) {
      float4 t = *(const float4*)&pa.W[k][(size_t)o * pa.Kr[k] + f];
      w[0] = t.x; w[1] = t.y; w[2] = t.z; w[3] = t.w;
    }
    f16x4 h4, l4;
#pragma unroll
    for (int e = 0; e < 4; ++e) {
      f16 h = (f16)w[e];
      float hf = (float)h;
      if (__builtin_fabsf(hf) < 6.103515625e-05f) { h = (f16)0.f; hf = 0.f; }
      h4[e] = h;
      l4[e] = (f16)((w[e] - hf) * 4096.0f);
    }
    int r2 = ((o >> 4) << 5) + (o & 15);
    *(f16x4*)&pa.dst[k][(size_t)r2 * Kp + f] = h4;
    *(f16x4*)&pa.dst[k][(size_t)(r2 + 16) * Kp + f] = l4;
  }
}

// ---------- merged Lk prep (k=1,2,3): [0,4096) gather spike cols | [4096,+) prep Wk rows ----------
__global__ __launch_bounds__(512) void prepk_all(const f16* __restrict__ src,
                                                 f16* __restrict__ dst,
                                                 const float* __restrict__ W,
                                                 f16* __restrict__ Wg,
                                                 const int* __restrict__ colidx,
                                                 const int* __restrict__ meta,
                                                 int srcW, int cstride, size_t astr,
                                                 int Nr, int Kr, size_t bstr) {
  __shared__ float row[2048];  // 8 KB (used by prep branch only)
  int blk = blockIdx.x;
  int tid = threadIdx.x;

  if (blk < 4096) {  // ---- gather_cols: one spike row ----
    int r = blk;
    int g = r >> 9;
    int K = meta[g * 2], Kpc = meta[g * 2 + 1];
    if (Kpc == 0) return;
    const int* cidx = colidx + g * cstride;
    const f16* s = src + (size_t)r * srcW;
    f16* d = dst + g * astr + (size_t)(r & 511) * Kpc;
    for (int j = tid; j < Kpc; j += 512)
      d[j] = (j < K) ? s[cidx[j]] : (f16)0.f;
    return;
  }

  {  // ---- prep_wk_row: one weight row, 8 per-group compact hi/lo rows ----
    int o = blk - 4096;
    bool live = (o < Nr);
    if (live) {
      for (int f4 = tid * 4; f4 < Kr; f4 += 2048)
        *(float4*)&row[f4] = *(const float4*)&W[(size_t)o * Kr + f4];
    }
    __syncthreads();
    int r2 = ((o >> 4) << 5) + (o & 15);
    for (int g = 0; g < 8; ++g) {
      int K = meta[g * 2], Kpc = meta[g * 2 + 1];
      const int* cidx = colidx + g * cstride;
      f16* dh = Wg + g * bstr + (size_t)r2 * Kpc;
      f16* dl = Wg + g * bstr + (size_t)(r2 + 16) * Kpc;
      for (int j = tid; j < Kpc; j += 512) {
        float w = 0.f;
        if (live && j < K) {
          int c = cidx[j];
          w = (c < Kr) ? row[c] : 0.f;
        }
        f16 h = (f16)w;
        float hf = (float)h;
        if (__builtin_fabsf(hf) < 6.103515625e-05f) { h = (f16)0.f; hf = 0.f; }
        dh[j] = h;
        dl[j] = (f16)((w - hf) * 4096.0f);
      }
    }
  }
}

// ---------- fused GEMM + LI_k + LIF_{k+1}, templated on wave-rows ----------
template <int WM>
__global__ __launch_bounds__(WM * 128, 4)
void gemm_fused(const f16* __restrict__ A, const f16* __restrict__ B2,
                f16* __restrict__ Spk, float* __restrict__ Out,
                const int* __restrict__ kpcp, int KpFixed, int Np,
                uint* __restrict__ colFlags, int cfw, int grouped,
                size_t astr, size_t bstr) {
  constexpr int BM = WM * 64;
  constexpr int NT = WM * 128;
  constexpr int BI = 1024 / NT;
  __shared__ f16 smem[BM * 64 + 128 * 64];
  f16* sA = smem;
  f16* sB = smem + BM * 64;
  const int tid = threadIdx.x;
  const int lane = tid & 63;
  const int wave = tid >> 6;
  const int wr = wave >> 1;
  const int wc = wave & 1;

  const int nx = gridDim.x;
  const int flat = blockIdx.y * nx + blockIdx.x;
  const int cpx = (nx * gridDim.y) >> 3;
  const int id = (flat & 7) * cpx + (flat >> 3);
  const int m0 = (id / nx) * BM;
  const int n0 = (id % nx) * 128;

  int Kp;
  size_t aoff, boff;
  if (grouped) {
    int g = m0 >> 9;
    Kp = kpcp[g * 2 + 1];
    aoff = g * astr + (size_t)(m0 & 511) * Kp;
    boff = g * bstr + (size_t)n0 * Kp;
  } else {
    Kp = kpcp ? kpcp[1] : KpFixed;
    aoff = (size_t)m0 * Kp;
    boff = (size_t)n0 * Kp;
  }

  f32x4 zero = {0.f, 0.f, 0.f, 0.f};
  f32x4 acc[4][4];
#pragma unroll
  for (int m = 0; m < 4; ++m)
#pragma unroll
    for (int n = 0; n < 4; ++n) acc[m][n] = zero;

  const f16* Abase = A + aoff;
  const f16* Bbase = B2 + boff;
  const int nkt = Kp >> 6;
  for (int kt = 0; kt < nkt; ++kt) {
    __syncthreads();
    const f16* Ab = Abase + (size_t)kt * 64;
    const f16* Bb = Bbase + (size_t)kt * 64;
#pragma unroll
    for (int j = 0; j < 4; ++j) {  // A: BM*8 chunks = 4*NT
      int q = j * NT + tid;
      int r = q >> 3, c = ((q & 7) ^ (r & 7)) * 8;
      __builtin_amdgcn_global_load_lds((const AS1 void*)(Ab + (size_t)r * Kp + c),
                                       (AS3 void*)(&sA[q * 8]), 16, 0, 0);
    }
#pragma unroll
    for (int j = 0; j < BI; ++j) {  // B: 1024 chunks
      int q = j * NT + tid;
      int r = q >> 3, c = ((q & 7) ^ (r & 7)) * 8;
      __builtin_amdgcn_global_load_lds((const AS1 void*)(Bb + (size_t)r * Kp + c),
                                       (AS3 void*)(&sB[q * 8]), 16, 0, 0);
    }
    __syncthreads();
#pragma unroll
    for (int kk = 0; kk < 2; ++kk) {
      const int lr = lane & 15;
      const int hq = lane >> 4;
      f16x8 af[4], bf[4];
#pragma unroll
      for (int m = 0; m < 4; ++m) {
        int R = wr * 64 + m * 16 + lr;
        int ch = (kk * 4 + hq) ^ (R & 7);
        af[m] = *(const f16x8*)&sA[R * 64 + ch * 8];
      }
#pragma unroll
      for (int n = 0; n < 4; ++n) {
        int R = wc * 64 + n * 16 + lr;
        int ch = (kk * 4 + hq) ^ (R & 7);
        bf[n] = *(const f16x8*)&sB[R * 64 + ch * 8];
      }
#pragma unroll
      for (int m = 0; m < 4; ++m)
#pragma unroll
        for (int n = 0; n < 4; ++n)
          acc[m][n] = __builtin_amdgcn_mfma_f32_16x16x32_f16(af[m], bf[n], acc[m][n], 0, 0, 0);
    }
  }

  const int lr = lane & 15, lq = lane >> 4;
  float* scr = (float*)smem + wave * 1152;  // [64][17] f32 per-wave scratch
  const int baseRow = m0 + wr * 64;

  if (Out) {  // last layer: fused LI5 scan + max + log_softmax
    __syncthreads();
#pragma unroll
    for (int m = 0; m < 4; ++m)
#pragma unroll
      for (int i = 0; i < 4; ++i)
        scr[(m * 16 + lq * 4 + i) * 17 + lr] = acc[m][0][i] + EPS_LO * acc[m][1][i];
    __syncthreads();
    float mx = -3.4e38f;
    if (lane < 32) {
      int bl = lane >> 4, c = lane & 15;
      float vL = 0.f, iL = 0.f;
      for (int t = 0; t < 32; ++t) {
        float g = scr[(bl * 32 + t) * 17 + c];
        float ij = iL + g;
        vL = vL + KM * (ij - vL);
        iL = KS * ij;
        mx = fmaxf(mx, vL);
      }
    }
    float v = (lane < 32 && (lane & 15) < 10) ? mx : -3.4e38f;
    float M = v;
#pragma unroll
    for (int s = 1; s < 16; s <<= 1) M = fmaxf(M, __shfl_xor(M, s));
    float e = (lane < 32 && (lane & 15) < 10) ? expf(v - M) : 0.f;
    float sum = e;
#pragma unroll
    for (int s = 1; s < 16; s <<= 1) sum += __shfl_xor(sum, s);
    if (n0 == 0 && wc == 0 && lane < 32 && (lane & 15) < 10) {
      int b = (baseRow >> 5) + (lane >> 4);
      Out[b * 10 + (lane & 15)] = v - M - logf(sum);
    }
    return;
  }

  // ---- fused LI+LIF epilogue: per wave, 64 rows (= 2 batches x 32 t) x 32 cols ----
  __syncthreads();
#pragma unroll
  for (int h = 0; h < 2; ++h) {
#pragma unroll
    for (int m = 0; m < 4; ++m)
#pragma unroll
      for (int i = 0; i < 4; ++i)
        scr[(m * 16 + lq * 4 + i) * 17 + lr] = acc[m][2 * h][i] + EPS_LO * acc[m][2 * h + 1][i];
    __syncthreads();
    if (lane < 32) {
      int bl = lane >> 4, c = lane & 15;
      float vL = 0.f, iL = 0.f, vF = 0.f, iF = 0.f;
      for (int t = 0; t < 32; ++t) {
        float g = scr[(bl * 32 + t) * 17 + c];
        float ij = iL + g;
        vL = vL + KM * (ij - vL);
        iL = KS * ij;
        float vd = vF + KM * (iF - vF);
        float idec = KS * iF;
        float z = (vd > 1.0f) ? 1.f : 0.f;
        vF = (1.f - z) * vd;
        iF = idec + vL;
        scr[(bl * 32 + t) * 17 + c] = z;
      }
    }
    __syncthreads();
    {
      int row = lane;
      f16x8 v0, v1;
#pragma unroll
      for (int cc = 0; cc < 8; ++cc) {
        v0[cc] = (f16)scr[row * 17 + cc];
        v1[cc] = (f16)scr[row * 17 + 8 + cc];
      }
      size_t go = (size_t)(baseRow + row) * Np + (n0 >> 1) + wc * 32 + h * 16;
      *(f16x8*)&Spk[go] = v0;
      *(f16x8*)&Spk[go + 8] = v1;
      if (colFlags) {  // per-group column spike-aliveness for next-layer K compaction
        uint bits = 0u;
#pragma unroll
        for (int cc = 0; cc < 8; ++cc) {
          bits |= (__any((float)v0[cc] != 0.f) ? 1u : 0u) << cc;
          bits |= (__any((float)v1[cc] != 0.f) ? 1u : 0u) << (8 + cc);
        }
        int cstart = (n0 >> 1) + wc * 32 + h * 16;  // multiple of 16
        int g1 = baseRow >> 9;
        if (lane == 0 && bits)
          atomicOr(&colFlags[g1 * cfw + (cstart >> 5)], bits << (cstart & 31));
      }
    }
    __syncthreads();
  }
}

extern "C" void kernel_launch(void* const* d_in, const int* in_sizes, int n_in,
                              void* d_out, int out_size, void* d_ws, size_t ws_size,
                              hipStream_t stream) {
  const float* img = (const float*)d_in[0];

  char* p = (char*)d_ws;
  f16* W0g = (f16*)p; p += 8 * (size_t)4096 * KCAP0 * 2;  // 160 MB
  f16* W1g = (f16*)p; p += 8 * (size_t)3072 * KCAP1 * 2;  // 100.7 MB
  f16* W2g = (f16*)p; p += 8 * (size_t)2048 * KCAP2 * 2;  // 33.6 MB
  f16* W3g = (f16*)p; p += 8 * (size_t)1024 * KCAP3 * 2;  // 16.8 MB
  f16* W4 = (f16*)p;  p += (size_t)2 * 128 * 512 * 2;
  f16* W5 = (f16*)p;  p += (size_t)2 * 128 * 128 * 2;
  f16* Ag = (f16*)p;  p += 8 * (size_t)512 * KCAP0 * 2;   // 21 MB
  f16* T0 = (f16*)p;  p += (size_t)4096 * 2048 * 2;       // 16.8 MB
  f16* T1 = (f16*)p;  p += (size_t)4096 * 2048 * 2;       // 16.8 MB
  uint* Z = (uint*)p; p += (size_t)128 * 12032 * 4;       // 6.2 MB
  uint* flagsB = (uint*)p; p += (size_t)128 * 375 * 4;    // per-batch L0-in flag words
  uint* flags1 = (uint*)p; p += 8 * 64 * 4;               // L1-in per-group flags
  uint* flags2 = (uint*)p; p += 8 * 48 * 4;               // L2-in per-group flags
  uint* flags3 = (uint*)p; p += 8 * 32 * 4;               // L3-in per-group flags
  int* colidx = (int*)p;  p += 8 * 12032 * 4;
  int* colidx1 = (int*)p; p += 8 * 2048 * 4;
  int* colidx2 = (int*)p; p += 8 * 1536 * 4;
  int* colidx3 = (int*)p; p += 8 * 1024 * 4;
  int* meta = (int*)p;  p += 16 * 4;
  int* meta1 = (int*)p; p += 16 * 4;
  int* meta2 = (int*)p; p += 16 * 4;
  int* meta3 = (int*)p; p += 16 * 4;

  // --- enc + L0 flag scan (flags1/2/3 zeroed inside enc_flags block 0) ---
  enc_flags<<<(128 * 3000 + 255) / 256, 256, 0, stream>>>(img, Z, flagsB, flags1,
                                                          8 * 64 + 8 * 48 + 8 * 32);
  scan_cols<<<8, 512, 0, stream>>>(flagsB, colidx, meta, 375, 12032, KCAP0, 16, 375);

  // --- merged L0 prep: W0 compaction + spike gather + L4-5 weight prep ---
  PrepArgs pa;
  static const int Nr2[2] = {100, 10}, Kr2[2] = {500, 100};
  static const int Kp2[2] = {512, 128}, Np2[2] = {128, 128};
  f16* dst2[2] = {W4, W5};
  int nb = 0;
  for (int k = 0; k < 2; ++k) {
    pa.W[k] = (const float*)d_in[k + 5];
    pa.dst[k] = dst2[k];
    pa.Nr[k] = Nr2[k]; pa.Kr[k] = Kr2[k]; pa.Kp[k] = Kp2[k]; pa.Npd[k] = Np2[k];
    pa.boff[k] = nb;
    nb += ((Np2[k] * Kp2[k]) >> 2) / 512;  // 32, 8 blocks
  }
  pa.boff[2] = nb;
  prep0_all<<<3072 + nb, 512, 0, stream>>>((const float*)d_in[1], W0g, Z, Ag,
                                           colidx, meta, pa);

  // --- L0: grouped GEMM + LI0/LIF1 epilogue + per-group flags1 ---
  gemm_fused<4><<<dim3(32, 16), dim3(512), 0, stream>>>(
      Ag, W0g, T0, nullptr, meta, 0, 2048, flags1, 64, 1,
      (size_t)512 * KCAP0, (size_t)4096 * KCAP0);

  // --- L1 per-group K-compaction (merged gather + prep) ---
  scan_cols<<<8, 512, 0, stream>>>(flags1, colidx1, meta1, 64, 2048, KCAP1, 1, 64);
  prepk_all<<<4096 + 1536, 512, 0, stream>>>(T0, T1, (const float*)d_in[2], W1g,
                                             colidx1, meta1, 2048, 2048,
                                             (size_t)512 * KCAP1, 1500, 2000,
                                             (size_t)3072 * KCAP1);

  // --- L1: grouped GEMM (WM=2 for exact 3 blocks/CU) + epilogue + per-group flags2 ---
  gemm_fused<2><<<dim3(24, 32), dim3(256), 0, stream>>>(
      T1, W1g, T0, nullptr, meta1, 0, 1536, flags2, 48, 1,
      (size_t)512 * KCAP1, (size_t)3072 * KCAP1);

  // --- L2 per-group K-compaction (merged gather + prep) ---
  scan_cols<<<8, 512, 0, stream>>>(flags2, colidx2, meta2, 48, 1536, KCAP2, 1, 48);
  prepk_all<<<4096 + 1024, 512, 0, stream>>>(T0, T1, (const float*)d_in[3], W2g,
                                             colidx2, meta2, 1536, 1536,
                                             (size_t)512 * KCAP2, 1000, 1500,
                                             (size_t)2048 * KCAP2);

  // --- L2: grouped GEMM + epilogue + per-group flags3 ---
  gemm_fused<2><<<dim3(16, 32), dim3(256), 0, stream>>>(
      T1, W2g, T0, nullptr, meta2, 0, 1024, flags3, 32, 1,
      (size_t)512 * KCAP2, (size_t)2048 * KCAP2);

  // --- L3 per-group K-compaction (merged gather + prep) ---
  scan_cols<<<8, 512, 0, stream>>>(flags3, colidx3, meta3, 32, 1024, KCAP3, 1, 32);
  prepk_all<<<4096 + 512, 512, 0, stream>>>(T0, T1, (const float*)d_in[4], W3g,
                                            colidx3, meta3, 1024, 1024,
                                            (size_t)512 * KCAP3, 500, 1000,
                                            (size_t)1024 * KCAP3);

  // --- L3: grouped GEMM ---
  gemm_fused<2><<<dim3(8, 32), dim3(256), 0, stream>>>(
      T1, W3g, T0, nullptr, meta3, 0, 512, nullptr, 0, 1,
      (size_t)512 * KCAP3, (size_t)1024 * KCAP3);

  // --- L4..L5 dense ---
  gemm_fused<2><<<dim3(2, 32), dim3(256), 0, stream>>>(
      T0, W4, T1, nullptr, nullptr, 512, 128, nullptr, 0, 0, 0, 0);
  gemm_fused<2><<<dim3(2, 32), dim3(256), 0, stream>>>(
      T1, W5, nullptr, (float*)d_out, nullptr, 128, 128, nullptr, 0, 0, 0, 0);
}